// Round 1
// baseline (623.947 us; speedup 1.0000x reference)
//
#include <hip/hip_runtime.h>
#include <cstdint>

#define TOK 16384
#define HD 2048
#define NE 64
#define HQ 512

// ---------------------------------------------------------------------------
// K1: router logits = hid @ rw^T  (f32), fused column-sum of hid for mean_h.
// grid 512 x 128 threads; tile 32 tokens x 64 experts; K-tile 32.
// A (hidden) staged in LDS (padded stride 36 -> 2-way max on reads);
// B (router_w) read direct from global (L2-resident, broadcast across lanes).
// micro-tile: 2 tokens x 8 experts per thread.
// ---------------------------------------------------------------------------
__global__ __launch_bounds__(128) void k_router(const float* __restrict__ hid,
                                                const float* __restrict__ rw,
                                                float* __restrict__ logits,
                                                float* __restrict__ colsum) {
  __shared__ float As[32][36];
  __shared__ float red[4][32];
  const int tid = threadIdx.x;
  const int t0 = blockIdx.x * 32;
  const int tr = tid >> 3;        // 0..15 (token pair)
  const int tc = tid & 7;         // 0..7  (expert group of 8)
  const int sr = tid >> 2;        // staging row 0..31
  const int sc = (tid & 3) * 8;   // staging col base
  const float* hrow = hid + (size_t)(t0 + sr) * HD + sc;

  float acc[2][8];
#pragma unroll
  for (int i = 0; i < 2; ++i)
#pragma unroll
    for (int j = 0; j < 8; ++j) acc[i][j] = 0.f;

  for (int kt = 0; kt < HD; kt += 32) {
    __syncthreads();
    // flush previous tile's column partials (written before the barrier)
    if (kt > 0 && tid < 32) {
      float s = red[0][tid] + red[1][tid] + red[2][tid] + red[3][tid];
      atomicAdd(&colsum[kt - 32 + tid], s);
    }
    float4 v0 = *(const float4*)(hrow + kt);
    float4 v1 = *(const float4*)(hrow + kt + 4);
    *(float4*)&As[sr][sc] = v0;
    *(float4*)&As[sr][sc + 4] = v1;
    __syncthreads();
    // column-sum partials for this tile (read-only on As, no barrier needed)
    {
      const int col = tid & 31, g = tid >> 5;
      float s = 0.f;
#pragma unroll
      for (int i = 0; i < 8; ++i) s += As[g * 8 + i][col];
      red[g][col] = s;
    }
    const float* rwb = rw + (size_t)(tc * 8) * HD + kt;
#pragma unroll
    for (int kk = 0; kk < 32; kk += 4) {
      float4 a0 = *(const float4*)&As[2 * tr][kk];
      float4 a1 = *(const float4*)&As[2 * tr + 1][kk];
#pragma unroll
      for (int j = 0; j < 8; ++j) {
        float4 b = *(const float4*)(rwb + (size_t)j * HD + kk);
        acc[0][j] += a0.x * b.x; acc[0][j] += a0.y * b.y;
        acc[0][j] += a0.z * b.z; acc[0][j] += a0.w * b.w;
        acc[1][j] += a1.x * b.x; acc[1][j] += a1.y * b.y;
        acc[1][j] += a1.z * b.z; acc[1][j] += a1.w * b.w;
      }
    }
  }
  __syncthreads();
  if (tid < 32) {
    float s = red[0][tid] + red[1][tid] + red[2][tid] + red[3][tid];
    atomicAdd(&colsum[HD - 32 + tid], s);
  }
#pragma unroll
  for (int i = 0; i < 2; ++i) {
    const int tok = t0 + 2 * tr + i;
    float4 lo = make_float4(acc[i][0], acc[i][1], acc[i][2], acc[i][3]);
    float4 hi = make_float4(acc[i][4], acc[i][5], acc[i][6], acc[i][7]);
    *(float4*)(logits + (size_t)tok * NE + tc * 8) = lo;
    *(float4*)(logits + (size_t)tok * NE + tc * 8 + 4) = hi;
  }
}

// ---------------------------------------------------------------------------
// K2a: h = relu(cap_w1 @ mean_h + b1), one block per output row (512 rows).
// ---------------------------------------------------------------------------
__global__ __launch_bounds__(256) void k_cap1(const float* __restrict__ w1,
                                              const float* __restrict__ b1,
                                              const float* __restrict__ colsum,
                                              float* __restrict__ h) {
  const int row = blockIdx.x;
  const int tid = threadIdx.x;
  const float invB = 1.0f / 16384.0f;
  const float* wr = w1 + (size_t)row * HD;
  float4 a0 = *(const float4*)(wr + tid * 4);
  float4 a1 = *(const float4*)(wr + 1024 + tid * 4);
  float4 c0 = *(const float4*)(colsum + tid * 4);
  float4 c1 = *(const float4*)(colsum + 1024 + tid * 4);
  float s = a0.x * (c0.x * invB) + a0.y * (c0.y * invB) +
            a0.z * (c0.z * invB) + a0.w * (c0.w * invB) +
            a1.x * (c1.x * invB) + a1.y * (c1.y * invB) +
            a1.z * (c1.z * invB) + a1.w * (c1.w * invB);
#pragma unroll
  for (int off = 32; off; off >>= 1) s += __shfl_down(s, off);
  __shared__ float wsum[4];
  if ((tid & 63) == 0) wsum[tid >> 6] = s;
  __syncthreads();
  if (tid == 0) {
    float t = wsum[0] + wsum[1] + wsum[2] + wsum[3] + b1[row];
    h[row] = fmaxf(t, 0.f);
  }
}

// ---------------------------------------------------------------------------
// K2b: cap_logits = cap_w2 @ h + b2, one block per expert.
// ---------------------------------------------------------------------------
__global__ __launch_bounds__(128) void k_cap2(const float* __restrict__ w2,
                                              const float* __restrict__ b2,
                                              const float* __restrict__ h,
                                              float* __restrict__ cl) {
  const int e = blockIdx.x, tid = threadIdx.x;
  float4 a = *(const float4*)(w2 + (size_t)e * HQ + tid * 4);
  float4 hv = *(const float4*)(h + tid * 4);
  float s = a.x * hv.x + a.y * hv.y + a.z * hv.z + a.w * hv.w;
#pragma unroll
  for (int off = 32; off; off >>= 1) s += __shfl_down(s, off);
  __shared__ float wsum[2];
  if ((tid & 63) == 0) wsum[tid >> 6] = s;
  __syncthreads();
  if (tid == 0) cl[e] = wsum[0] + wsum[1] + b2[e];
}

// ---------------------------------------------------------------------------
// K2c: softmax(cap_logits) -> clip -> capacity (int floor), one wave.
// ---------------------------------------------------------------------------
__global__ __launch_bounds__(64) void k_capacity(const float* __restrict__ cl,
                                                 int* __restrict__ cap) {
  const int tid = threadIdx.x;
  float l = cl[tid];
  float m = l;
#pragma unroll
  for (int off = 1; off < 64; off <<= 1) m = fmaxf(m, __shfl_xor(m, off));
  float ex = expf(l - m);
  float s = ex;
#pragma unroll
  for (int off = 1; off < 64; off <<= 1) s += __shfl_xor(s, off);
  float w = ex / s;
  float cf = 1.25f + (w - 0.5f) * 1.0f;
  cf = fminf(fmaxf(cf, 1.0f), 2.0f);
  cap[tid] = (int)floorf(16384.0f * cf / 64.0f);
}

// ---------------------------------------------------------------------------
// K3a: per-token softmax over 64 experts; writes probsT [E][B]; entropy accum.
// 64 tokens/block; 4 threads per token, 16 experts each.
// ---------------------------------------------------------------------------
__global__ __launch_bounds__(256) void k_softmax(const float* __restrict__ logits,
                                                 float* __restrict__ probsT,
                                                 float* __restrict__ ent) {
  __shared__ float tp[64][65];
  __shared__ float lent;
  const int tid = threadIdx.x;
  const int t0 = blockIdx.x * 64;
  const int tl = tid >> 2, q = tid & 3;
  const int t = t0 + tl;
  if (tid == 0) lent = 0.f;
  const float* lr = logits + (size_t)t * NE + q * 16;
  float4 v0 = *(const float4*)(lr);
  float4 v1 = *(const float4*)(lr + 4);
  float4 v2 = *(const float4*)(lr + 8);
  float4 v3 = *(const float4*)(lr + 12);
  float p[16] = {v0.x, v0.y, v0.z, v0.w, v1.x, v1.y, v1.z, v1.w,
                 v2.x, v2.y, v2.z, v2.w, v3.x, v3.y, v3.z, v3.w};
  float m = p[0];
#pragma unroll
  for (int i = 1; i < 16; ++i) m = fmaxf(m, p[i]);
  m = fmaxf(m, __shfl_xor(m, 1));
  m = fmaxf(m, __shfl_xor(m, 2));
  float s = 0.f;
#pragma unroll
  for (int i = 0; i < 16; ++i) { p[i] = expf(p[i] - m); s += p[i]; }
  s += __shfl_xor(s, 1);
  s += __shfl_xor(s, 2);
  const float inv = 1.0f / s;
  float el = 0.f;
#pragma unroll
  for (int i = 0; i < 16; ++i) {
    float pp = p[i] * inv;
    p[i] = pp;
    el += pp * logf(pp + 1e-8f);
  }
  el += __shfl_xor(el, 1);
  el += __shfl_xor(el, 2);
#pragma unroll
  for (int i = 0; i < 16; ++i) tp[q * 16 + i][tl] = p[i];
  __syncthreads();
  if (q == 0) atomicAdd(&lent, el);
  const int er = tid >> 6, tl2 = tid & 63;
#pragma unroll
  for (int pass = 0; pass < 16; ++pass) {
    const int e = pass * 4 + er;
    probsT[(size_t)e * TOK + t0 + tl2] = tp[e][tl2];
  }
  __syncthreads();
  if (tid == 0) atomicAdd(ent, lent);
}

// ---------------------------------------------------------------------------
// K3b: per-expert exact k-th largest prob (radix select on float bits) +
// stable-sort tie cutoff index. One block per expert.
// ---------------------------------------------------------------------------
__global__ __launch_bounds__(256) void k_selthr(const float* __restrict__ probsT,
                                                const int* __restrict__ cap,
                                                unsigned* __restrict__ thrT,
                                                int* __restrict__ cutoff) {
  const int e = blockIdx.x, tid = threadIdx.x;
  const unsigned* col = (const unsigned*)(probsT + (size_t)e * TOK);
  __shared__ unsigned hist[256];
  __shared__ unsigned sh_pref;
  __shared__ int sh_rem;
  __shared__ int sred[4];
  __shared__ int sgt[4], seq2[4];
  const int k = cap[e];
  unsigned prefix = 0, pmask = 0;
  int rem = k;
  for (int pass = 0; pass < 4; ++pass) {
    const int shift = 24 - 8 * pass;
    hist[tid] = 0;
    __syncthreads();
    for (int i = tid; i < TOK; i += 256) {
      unsigned v = col[i];
      if ((v & pmask) == prefix) atomicAdd(&hist[(v >> shift) & 255u], 1u);
    }
    __syncthreads();
    if (tid == 0) {
      int cum = 0, b = 255;
      for (; b > 0; --b) {
        int c = (int)hist[b];
        if (cum + c >= rem) break;
        cum += c;
      }
      sh_pref = prefix | ((unsigned)b << shift);
      sh_rem = rem - cum;
    }
    __syncthreads();
    prefix = sh_pref;
    rem = sh_rem;
    pmask |= 255u << shift;
    __syncthreads();
  }
  const unsigned T = prefix;
  int lgt = 0, leq = 0;
  for (int i = tid; i < TOK; i += 256) {
    unsigned v = col[i];
    lgt += (v > T);
    leq += (v == T);
  }
#pragma unroll
  for (int off = 32; off; off >>= 1) {
    lgt += __shfl_down(lgt, off);
    leq += __shfl_down(leq, off);
  }
  if ((tid & 63) == 0) { sgt[tid >> 6] = lgt; seq2[tid >> 6] = leq; }
  __syncthreads();
  const int c_gt = sgt[0] + sgt[1] + sgt[2] + sgt[3];
  const int c_eq = seq2[0] + seq2[1] + seq2[2] + seq2[3];
  const int n_allowed = k - c_gt;
  int cut;
  if (n_allowed <= 0) {
    cut = -1;
  } else if (c_eq <= n_allowed) {
    cut = 0x7fffffff;
  } else {
    // smallest X with #{i <= X : col[i]==T} >= n_allowed (rare tie path)
    int lo = 0, hi = TOK - 1;
    while (lo < hi) {
      const int mid = (lo + hi) >> 1;
      int c = 0;
      for (int i = tid; i <= mid; i += 256) c += (col[i] == T);
#pragma unroll
      for (int off = 32; off; off >>= 1) c += __shfl_down(c, off);
      __syncthreads();
      if ((tid & 63) == 0) sred[tid >> 6] = c;
      __syncthreads();
      const int cnt = sred[0] + sred[1] + sred[2] + sred[3];
      if (cnt >= n_allowed) hi = mid; else lo = mid + 1;
    }
    cut = lo;
  }
  if (tid == 0) { thrT[e] = T; cutoff[e] = cut; }
}

// ---------------------------------------------------------------------------
// K3c: per-token selection (max expert with token in its top-capacity set),
// weight gather, entropy finalize. 64 tokens/block.
// ---------------------------------------------------------------------------
__global__ __launch_bounds__(256) void k_final(const float* __restrict__ probsT,
                                               const unsigned* __restrict__ thrT,
                                               const int* __restrict__ cutoff,
                                               const float* __restrict__ ent,
                                               float* __restrict__ out_sel,
                                               float* __restrict__ out_w,
                                               float* __restrict__ out_ent) {
  __shared__ float tp[64][65];
  __shared__ unsigned sT[64];
  __shared__ int sC[64];
  const int tid = threadIdx.x;
  const int t0 = blockIdx.x * 64;
  if (tid < 64) { sT[tid] = thrT[tid]; sC[tid] = cutoff[tid]; }
  const int er = tid >> 6, tl2 = tid & 63;
#pragma unroll
  for (int pass = 0; pass < 16; ++pass) {
    const int e = pass * 4 + er;
    tp[e][tl2] = probsT[(size_t)e * TOK + t0 + tl2];
  }
  __syncthreads();
  const int tl = tid >> 2, q = tid & 3;
  const int t_abs = t0 + tl;
  int best = -1;
  float bw = 0.f;
  for (int i = 15; i >= 0; --i) {
    const int e = q * 16 + i;
    const float p = tp[e][tl];
    const unsigned v = __float_as_uint(p);
    const unsigned T = sT[e];
    if (v > T || (v == T && t_abs <= sC[e])) { best = e; bw = p; break; }
  }
#pragma unroll
  for (int off = 1; off <= 2; off <<= 1) {
    const int b2 = __shfl_xor(best, off);
    const float w2 = __shfl_xor(bw, off);
    if (b2 > best) { best = b2; bw = w2; }
  }
  if (q == 0) {
    out_sel[t_abs] = (float)(best >= 0 ? best : 0);
    out_w[t_abs] = (best >= 0 ? bw : 0.0f);
  }
  if (blockIdx.x == 0 && tid == 0) out_ent[0] = -ent[0] / 16384.0f;
}

// ---------------------------------------------------------------------------
extern "C" void kernel_launch(void* const* d_in, const int* in_sizes, int n_in,
                              void* d_out, int out_size, void* d_ws, size_t ws_size,
                              hipStream_t stream) {
  const float* hid = (const float*)d_in[0];
  const float* rw  = (const float*)d_in[1];
  const float* w1  = (const float*)d_in[2];
  const float* b1  = (const float*)d_in[3];
  const float* w2  = (const float*)d_in[4];
  const float* b2  = (const float*)d_in[5];
  float* out = (float*)d_out;
  float* logits  = out;
  float* out_sel = out + (size_t)TOK * NE;
  float* out_w   = out_sel + TOK;
  float* out_ent = out_w + TOK;
  char* ws = (char*)d_ws;
  float*    colsum = (float*)(ws + 0);       // 2048 f32
  float*    ent    = (float*)(ws + 8192);    // 1 f32
  float*    h      = (float*)(ws + 8448);    // 512 f32
  float*    cl     = (float*)(ws + 10496);   // 64 f32
  int*      cap    = (int*)(ws + 10752);     // 64 i32
  unsigned* thr    = (unsigned*)(ws + 11008);// 64 u32
  int*      cut    = (int*)(ws + 11264);     // 64 i32
  float*    probsT = (float*)(ws + 16384);   // 64*16384 f32 = 4 MiB

  hipMemsetAsync(d_ws, 0, 8448, stream);  // zero colsum + entropy accumulator
  hipLaunchKernelGGL(k_router, dim3(TOK / 32), dim3(128), 0, stream, hid, rw, logits, colsum);
  hipLaunchKernelGGL(k_cap1, dim3(HQ), dim3(256), 0, stream, w1, b1, colsum, h);
  hipLaunchKernelGGL(k_cap2, dim3(NE), dim3(128), 0, stream, w2, b2, h, cl);
  hipLaunchKernelGGL(k_capacity, dim3(1), dim3(64), 0, stream, cl, cap);
  hipLaunchKernelGGL(k_softmax, dim3(TOK / 64), dim3(256), 0, stream, logits, probsT, ent);
  hipLaunchKernelGGL(k_selthr, dim3(NE), dim3(256), 0, stream, probsT, cap, thr, cut);
  hipLaunchKernelGGL(k_final, dim3(TOK / 64), dim3(256), 0, stream, probsT, thr, cut, ent, out_sel, out_w, out_ent);
}